// Round 1
// baseline (1766.646 us; speedup 1.0000x reference)
//
#include <hip/hip_runtime.h>
#include <math.h>

#define DIMM 256
#define HEADS 8
#define HD 32
#define NB 2048
#define BB 2
#define ROWS (BB*NB)   // 4096

// ---------------- mask format handling ----------------
// node_mask is bool in the reference. Harness may deliver it as 1-byte bool
// or as int32. Detect on device: if int32 with values 0/1, bytes at offset
// 4i+1 are all zero; if bool8, ~half of them are 1.
__global__ __launch_bounds__(256) void detect_mask_fmt(const unsigned char* __restrict__ nm,
                                                       int* __restrict__ flag) {
    __shared__ int red[256];
    int t = threadIdx.x;
    int cnt = 0;
    for (int i = t; i < 1024; i += 256) cnt += (nm[4*i + 1] != 0) ? 1 : 0;
    red[t] = cnt;
    __syncthreads();
    for (int s = 128; s > 0; s >>= 1) {
        if (t < s) red[t] += red[t + s];
        __syncthreads();
    }
    if (t == 0) *flag = (red[0] > 0) ? 1 : 0;   // 1 => bool8, 0 => int32
}

__device__ inline int get_mask(const void* nm, int fmt, int idx) {
    if (fmt) return ((const unsigned char*)nm)[idx] != 0;
    return ((const int*)nm)[idx] != 0;
}

// ---------------- LayerNorm ----------------
__global__ __launch_bounds__(256) void ln_kernel(const float* __restrict__ x,
                                                 const float* __restrict__ g,
                                                 const float* __restrict__ b,
                                                 float* __restrict__ out) {
    int row = blockIdx.x;
    int t = threadIdx.x;
    float v = x[(size_t)row * DIMM + t];
    float s = v, s2 = v * v;
#pragma unroll
    for (int off = 32; off >= 1; off >>= 1) {
        s  += __shfl_xor(s,  off, 64);
        s2 += __shfl_xor(s2, off, 64);
    }
    __shared__ float rs[8];
    int wave = t >> 6;
    if ((t & 63) == 0) { rs[wave * 2] = s; rs[wave * 2 + 1] = s2; }
    __syncthreads();
    float ts  = rs[0] + rs[2] + rs[4] + rs[6];
    float ts2 = rs[1] + rs[3] + rs[5] + rs[7];
    float mean = ts * (1.0f / DIMM);
    float var  = ts2 * (1.0f / DIMM) - mean * mean;
    float rstd = rsqrtf(var + 1e-5f);
    out[(size_t)row * DIMM + t] = (v - mean) * rstd * g[t] + b[t];
}

// ---------------- Tiled fp32 GEMM, C = A[M,K] @ B[K,N] + bias, fused epilogues -------
// EPI 0: bias only
// EPI 1: (acc+bias)*mask[row] + resid[row,col]
// EPI 2: gelu_exact(acc+bias)
template<int EPI>
__global__ __launch_bounds__(256) void gemm_kernel(
    const float* __restrict__ A, const float* __restrict__ Bw,
    const float* __restrict__ bias, float* __restrict__ C,
    int M, int Ncols, int K,
    const float* __restrict__ resid, const void* __restrict__ nmask,
    const int* __restrict__ fmt)
{
    __shared__ float As[16][68];   // [k][m], padded to keep 16B alignment + kill conflicts
    __shared__ float Bs[16][64];   // [k][n]
    int t  = threadIdx.x;
    int m0 = blockIdx.y * 64, n0 = blockIdx.x * 64;
    int ty = t >> 4, tx = t & 15;
    int ar = t >> 2, ac4 = t & 3;
    int br = t >> 4, bc4 = t & 15;
    float acc[4][4] = {};

    for (int k0 = 0; k0 < K; k0 += 16) {
        float4 a4 = *(const float4*)&A[(size_t)(m0 + ar) * K + k0 + ac4 * 4];
        As[ac4 * 4 + 0][ar] = a4.x;
        As[ac4 * 4 + 1][ar] = a4.y;
        As[ac4 * 4 + 2][ar] = a4.z;
        As[ac4 * 4 + 3][ar] = a4.w;
        float4 b4 = *(const float4*)&Bw[(size_t)(k0 + br) * Ncols + n0 + bc4 * 4];
        *(float4*)&Bs[br][bc4 * 4] = b4;
        __syncthreads();
#pragma unroll
        for (int kk = 0; kk < 16; ++kk) {
            float4 av = *(const float4*)&As[kk][ty * 4];
            float4 bv = *(const float4*)&Bs[kk][tx * 4];
            float a[4] = {av.x, av.y, av.z, av.w};
            float bb[4] = {bv.x, bv.y, bv.z, bv.w};
#pragma unroll
            for (int i = 0; i < 4; ++i)
#pragma unroll
                for (int j = 0; j < 4; ++j) acc[i][j] += a[i] * bb[j];
        }
        __syncthreads();
    }

    int fm = (EPI == 1) ? *fmt : 0;
#pragma unroll
    for (int i = 0; i < 4; ++i) {
        int row = m0 + ty * 4 + i;
        float mk = 1.0f;
        if (EPI == 1) mk = (float)get_mask(nmask, fm, row);
#pragma unroll
        for (int j = 0; j < 4; ++j) {
            int col = n0 + tx * 4 + j;
            float v = acc[i][j] + bias[col];
            if (EPI == 2) v = 0.5f * v * (1.0f + erff(v * 0.70710678118654752f));
            if (EPI == 1) v = v * mk + resid[(size_t)row * Ncols + col];
            C[(size_t)row * Ncols + col] = v;
        }
    }
}

// ---------------- Fused attention: one block per (b, qi) ----------------
// qkv layout per row: [q(0:256) | k(256:512) | v(512:768)], inner h*32+d
__global__ __launch_bounds__(256) void attn_kernel(
    const float* __restrict__ qkv, const int* __restrict__ etypes,
    const float* __restrict__ table, const void* __restrict__ nmask,
    const int* __restrict__ fmt, float* __restrict__ out)
{
    __shared__ float sc[HEADS * NB];   // 64 KB: scores then probabilities
    int qi = blockIdx.x, b = blockIdx.y;
    int t = threadIdx.x;
    int fm = *fmt;
    int row = b * NB + qi;
    if (!get_mask(nmask, fm, row)) {
        // proj epilogue multiplies by mask=0; write zeros to stay finite
        out[(size_t)row * DIMM + t] = 0.0f;
        return;
    }
    int h = t >> 5, l = t & 31;

    // q fragment for this head in registers
    float4 q4[8];
    const float4* qp = (const float4*)(qkv + (size_t)row * 768 + h * HD);
#pragma unroll
    for (int i = 0; i < 8; ++i) q4[i] = qp[i];

    const float scale = 0.17677669529663689f;   // 1/sqrt(32)
    float lmax = -1e30f;
    // Phase A: scores. lane l handles m = j*32 + l
    for (int j = 0; j < NB / 32; ++j) {
        int m = j * 32 + l;
        int et = etypes[(size_t)row * NB + m];
        int valid = ((et != 0) || (m == qi)) && get_mask(nmask, fm, b * NB + m);
        float s;
        if (valid) {
            const float4* kp = (const float4*)(qkv + (size_t)(b * NB + m) * 768 + 256 + h * HD);
            float dacc = 0.0f;
#pragma unroll
            for (int i = 0; i < 8; ++i) {
                float4 kv = kp[i];
                dacc += q4[i].x * kv.x + q4[i].y * kv.y + q4[i].z * kv.z + q4[i].w * kv.w;
            }
            s = dacc * scale + table[et * HEADS + h];
        } else {
            s = -1e9f;
        }
        sc[h * NB + m] = s;
        lmax = fmaxf(lmax, s);
    }
    // Phase B: softmax within each head's 32-lane group
#pragma unroll
    for (int off = 16; off >= 1; off >>= 1) lmax = fmaxf(lmax, __shfl_xor(lmax, off, 32));
    float lsum = 0.0f;
    for (int j = 0; j < NB / 32; ++j) {
        int m = j * 32 + l;
        float p = __expf(sc[h * NB + m] - lmax);   // masked -> exp(-1e9-..) == 0
        sc[h * NB + m] = p;
        lsum += p;
    }
#pragma unroll
    for (int off = 16; off >= 1; off >>= 1) lsum += __shfl_xor(lsum, off, 32);
    float rinv = 1.0f / lsum;   // >= 1 always (max element contributes 1)
    __syncthreads();

    // Phase C: out[h][d] = sum_m p[h][m] * v[b,m,h,d];  thread: h = t>>5, d = l
    float acc = 0.0f;
    for (int m = 0; m < NB; ++m) {
        float p = sc[h * NB + m];
        if (p != 0.0f) {   // wave-uniform skip for node-masked keys
            acc += p * qkv[(size_t)(b * NB + m) * 768 + 512 + h * HD + l];
        }
    }
    out[(size_t)row * DIMM + t] = acc * rinv;
}

// ---------------- launch ----------------
extern "C" void kernel_launch(void* const* d_in, const int* in_sizes, int n_in,
                              void* d_out, int out_size, void* d_ws, size_t ws_size,
                              hipStream_t stream) {
    const float* x       = (const float*)d_in[0];
    const int*   etypes  = (const int*)d_in[1];
    const void*  nmask   = d_in[2];
    const float* qkv_w   = (const float*)d_in[3];
    const float* qkv_b   = (const float*)d_in[4];
    const float* proj_w  = (const float*)d_in[5];
    const float* proj_b  = (const float*)d_in[6];
    const float* table   = (const float*)d_in[7];
    const float* ln1_g   = (const float*)d_in[8];
    const float* ln1_b   = (const float*)d_in[9];
    const float* ln2_g   = (const float*)d_in[10];
    const float* ln2_b   = (const float*)d_in[11];
    const float* ffn_w1  = (const float*)d_in[12];
    const float* ffn_b1  = (const float*)d_in[13];
    const float* ffn_w2  = (const float*)d_in[14];
    const float* ffn_b2  = (const float*)d_in[15];
    float* out = (float*)d_out;
    float* ws  = (float*)d_ws;

    float* h_ln   = ws;                 // 1,048,576 floats
    float* qkv    = ws + 1048576;       // 3,145,728
    float* attn_o = ws + 4194304;       // 1,048,576
    float* x1     = ws + 5242880;       // 1,048,576
    float* mid    = ws + 6291456;       // 4,194,304
    int*   flag   = (int*)(ws + 10485760);

    detect_mask_fmt<<<dim3(1), dim3(256), 0, stream>>>((const unsigned char*)nmask, flag);

    // h = LN1(x)
    ln_kernel<<<dim3(ROWS), dim3(256), 0, stream>>>(x, ln1_g, ln1_b, h_ln);
    // qkv = h @ qkv_w + qkv_b
    gemm_kernel<0><<<dim3(768/64, ROWS/64), dim3(256), 0, stream>>>(
        h_ln, qkv_w, qkv_b, qkv, ROWS, 768, 256, nullptr, nullptr, flag);
    // attention
    attn_kernel<<<dim3(NB, BB), dim3(256), 0, stream>>>(qkv, etypes, table, nmask, flag, attn_o);
    // x1 = x + (attn_o @ proj_w + proj_b) * mask
    gemm_kernel<1><<<dim3(256/64, ROWS/64), dim3(256), 0, stream>>>(
        attn_o, proj_w, proj_b, x1, ROWS, 256, 256, x, nmask, flag);
    // h = LN2(x1)
    ln_kernel<<<dim3(ROWS), dim3(256), 0, stream>>>(x1, ln2_g, ln2_b, h_ln);
    // mid = gelu(h @ ffn_w1 + ffn_b1)
    gemm_kernel<2><<<dim3(1024/64, ROWS/64), dim3(256), 0, stream>>>(
        h_ln, ffn_w1, ffn_b1, mid, ROWS, 1024, 256, nullptr, nullptr, flag);
    // out = x1 + (mid @ ffn_w2 + ffn_b2) * mask
    gemm_kernel<1><<<dim3(256/64, ROWS/64), dim3(256), 0, stream>>>(
        mid, ffn_w2, ffn_b2, out, ROWS, 256, 1024, x1, nmask, flag);
}

// Round 2
// 477.417 us; speedup vs baseline: 3.7004x; 3.7004x over previous
//
#include <hip/hip_runtime.h>
#include <math.h>

#define DIMM 256
#define HEADS 8
#define HD 32
#define NB 2048
#define BB 2
#define ROWS (BB*NB)   // 4096
#define TQ 64
#define TK 64

// ---------------- mask format handling ----------------
__global__ __launch_bounds__(256) void detect_mask_fmt(const unsigned char* __restrict__ nm,
                                                       int* __restrict__ flag) {
    __shared__ int red[256];
    int t = threadIdx.x;
    int cnt = 0;
    for (int i = t; i < 1024; i += 256) cnt += (nm[4*i + 1] != 0) ? 1 : 0;
    red[t] = cnt;
    __syncthreads();
    for (int s = 128; s > 0; s >>= 1) {
        if (t < s) red[t] += red[t + s];
        __syncthreads();
    }
    if (t == 0) *flag = (red[0] > 0) ? 1 : 0;   // 1 => bool8, 0 => int32
}

__device__ inline int get_mask(const void* nm, int fmt, int idx) {
    if (fmt) return ((const unsigned char*)nm)[idx] != 0;
    return ((const int*)nm)[idx] != 0;
}

// ---------------- LayerNorm ----------------
__global__ __launch_bounds__(256) void ln_kernel(const float* __restrict__ x,
                                                 const float* __restrict__ g,
                                                 const float* __restrict__ b,
                                                 float* __restrict__ out) {
    int row = blockIdx.x;
    int t = threadIdx.x;
    float v = x[(size_t)row * DIMM + t];
    float s = v, s2 = v * v;
#pragma unroll
    for (int off = 32; off >= 1; off >>= 1) {
        s  += __shfl_xor(s,  off, 64);
        s2 += __shfl_xor(s2, off, 64);
    }
    __shared__ float rs[8];
    int wave = t >> 6;
    if ((t & 63) == 0) { rs[wave * 2] = s; rs[wave * 2 + 1] = s2; }
    __syncthreads();
    float ts  = rs[0] + rs[2] + rs[4] + rs[6];
    float ts2 = rs[1] + rs[3] + rs[5] + rs[7];
    float mean = ts * (1.0f / DIMM);
    float var  = ts2 * (1.0f / DIMM) - mean * mean;
    float rstd = rsqrtf(var + 1e-5f);
    out[(size_t)row * DIMM + t] = (v - mean) * rstd * g[t] + b[t];
}

// ---------------- Tiled fp32 GEMM (unchanged from R1) ----------------
template<int EPI>
__global__ __launch_bounds__(256) void gemm_kernel(
    const float* __restrict__ A, const float* __restrict__ Bw,
    const float* __restrict__ bias, float* __restrict__ C,
    int M, int Ncols, int K,
    const float* __restrict__ resid, const void* __restrict__ nmask,
    const int* __restrict__ fmt)
{
    __shared__ float As[16][68];
    __shared__ float Bs[16][64];
    int t  = threadIdx.x;
    int m0 = blockIdx.y * 64, n0 = blockIdx.x * 64;
    int ty = t >> 4, tx = t & 15;
    int ar = t >> 2, ac4 = t & 3;
    int br = t >> 4, bc4 = t & 15;
    float acc[4][4] = {};

    for (int k0 = 0; k0 < K; k0 += 16) {
        float4 a4 = *(const float4*)&A[(size_t)(m0 + ar) * K + k0 + ac4 * 4];
        As[ac4 * 4 + 0][ar] = a4.x;
        As[ac4 * 4 + 1][ar] = a4.y;
        As[ac4 * 4 + 2][ar] = a4.z;
        As[ac4 * 4 + 3][ar] = a4.w;
        float4 b4 = *(const float4*)&Bw[(size_t)(k0 + br) * Ncols + n0 + bc4 * 4];
        *(float4*)&Bs[br][bc4 * 4] = b4;
        __syncthreads();
#pragma unroll
        for (int kk = 0; kk < 16; ++kk) {
            float4 av = *(const float4*)&As[kk][ty * 4];
            float4 bv = *(const float4*)&Bs[kk][tx * 4];
            float a[4] = {av.x, av.y, av.z, av.w};
            float bb[4] = {bv.x, bv.y, bv.z, bv.w};
#pragma unroll
            for (int i = 0; i < 4; ++i)
#pragma unroll
                for (int j = 0; j < 4; ++j) acc[i][j] += a[i] * bb[j];
        }
        __syncthreads();
    }

    int fm = (EPI == 1) ? *fmt : 0;
#pragma unroll
    for (int i = 0; i < 4; ++i) {
        int row = m0 + ty * 4 + i;
        float mk = 1.0f;
        if (EPI == 1) mk = (float)get_mask(nmask, fm, row);
#pragma unroll
        for (int j = 0; j < 4; ++j) {
            int col = n0 + tx * 4 + j;
            float v = acc[i][j] + bias[col];
            if (EPI == 2) v = 0.5f * v * (1.0f + erff(v * 0.70710678118654752f));
            if (EPI == 1) v = v * mk + resid[(size_t)row * Ncols + col];
            C[(size_t)row * Ncols + col] = v;
        }
    }
}

// ---------------- Flash-style fused attention ----------------
// Block = (q-tile of 64, head h, batch b). 256 threads = 4 waves.
// No max-subtraction: scores provably tiny (|s| < ~1); masked addend -1e9
// underflows expf to exact 0. Row-sum l kept in registers across all steps.
__global__ __launch_bounds__(256) void attn_flash(
    const float* __restrict__ qkv, const int* __restrict__ etypes,
    const float* __restrict__ table, const void* __restrict__ nmask,
    const int* __restrict__ fmt, float* __restrict__ out)
{
    __shared__ float QT[32][68];      // k-major Q tile
    __shared__ float KT[32][68];      // k-major K tile
    __shared__ float V[TK][36];       // row-major V tile
    __shared__ float P[TQ][68];       // addend -> probs
    __shared__ float tab[72];
    __shared__ float lsum[TQ][17];    // final l reduction

    int t  = threadIdx.x;
    int qt = blockIdx.x, h = blockIdx.y, b = blockIdx.z;
    int q0 = qt * TQ;
    int fm = *fmt;
    const float scale = 0.17677669529663689f;   // 1/sqrt(32)

    if (t < 72) tab[t] = table[t];

    // preload QT (k-major): 512 float4 total
#pragma unroll
    for (int rep = 0; rep < 2; ++rep) {
        int idx = t + rep * 256;
        int m = idx >> 3, k4 = idx & 7;
        float4 g = *(const float4*)(qkv + (size_t)(b * NB + q0 + m) * 768 + h * HD + k4 * 4);
        QT[k4 * 4 + 0][m] = g.x;
        QT[k4 * 4 + 1][m] = g.y;
        QT[k4 * 4 + 2][m] = g.z;
        QT[k4 * 4 + 3][m] = g.w;
    }

    int ty = t >> 4, tx = t & 15;     // S microtile: rows 4ty+i, cols 4tx+j
    int cr = t >> 2, cs = t & 3;      // addend crew: row cr, col-segment cs*16
    int pr = t >> 3, pd = (t & 7) * 4; // PV: rows 2pr,2pr+1, dims pd..pd+3

    float lacc[4] = {0.f, 0.f, 0.f, 0.f};
    float4 Oa0 = {0.f, 0.f, 0.f, 0.f};
    float4 Oa1 = {0.f, 0.f, 0.f, 0.f};

    for (int m0 = 0; m0 < NB; m0 += TK) {
        __syncthreads();   // previous iter's P/KT/V reads complete

        // ---- load K,V tiles ----
#pragma unroll
        for (int rep = 0; rep < 2; ++rep) {
            int idx = t + rep * 256;
            int m = idx >> 3, k4 = idx & 7;
            const float* base = qkv + (size_t)(b * NB + m0 + m) * 768 + h * HD;
            float4 gk = *(const float4*)(base + 256 + k4 * 4);
            KT[k4 * 4 + 0][m] = gk.x;
            KT[k4 * 4 + 1][m] = gk.y;
            KT[k4 * 4 + 2][m] = gk.z;
            KT[k4 * 4 + 3][m] = gk.w;
            float4 gv = *(const float4*)(base + 512 + k4 * 4);
            *(float4*)&V[m][k4 * 4] = gv;
        }
        // ---- addend tile: bias if valid else -1e9 ----
        {
            const int* ebase = etypes + (size_t)(b * NB + q0 + cr) * NB + m0 + cs * 16;
#pragma unroll
            for (int c4 = 0; c4 < 4; ++c4) {
                int4 e4 = *(const int4*)(ebase + c4 * 4);
                int ee[4] = {e4.x, e4.y, e4.z, e4.w};
                float f[4];
#pragma unroll
                for (int u = 0; u < 4; ++u) {
                    int cc = cs * 16 + c4 * 4 + u;
                    int m = m0 + cc;
                    int valid = ((ee[u] != 0) || (m == q0 + cr)) && get_mask(nmask, fm, b * NB + m);
                    f[u] = valid ? tab[ee[u] * 8 + h] : -1e9f;
                }
                float4 fv = {f[0], f[1], f[2], f[3]};
                *(float4*)&P[cr][cs * 16 + c4 * 4] = fv;
            }
        }
        __syncthreads();   // KT, V, addend ready

        // ---- S = Q K^T (4x4 microtile), then P = exp(s*scale + addend) ----
        float s[4][4] = {};
#pragma unroll 8
        for (int k = 0; k < 32; ++k) {
            float4 qv = *(const float4*)&QT[k][4 * ty];
            float4 kv = *(const float4*)&KT[k][4 * tx];
            float qa[4] = {qv.x, qv.y, qv.z, qv.w};
            float kb[4] = {kv.x, kv.y, kv.z, kv.w};
#pragma unroll
            for (int i = 0; i < 4; ++i)
#pragma unroll
                for (int j = 0; j < 4; ++j) s[i][j] += qa[i] * kb[j];
        }
#pragma unroll
        for (int i = 0; i < 4; ++i) {
            float4 ad = *(const float4*)&P[4 * ty + i][4 * tx];
            float4 p;
            p.x = __expf(fmaf(s[i][0], scale, ad.x));
            p.y = __expf(fmaf(s[i][1], scale, ad.y));
            p.z = __expf(fmaf(s[i][2], scale, ad.z));
            p.w = __expf(fmaf(s[i][3], scale, ad.w));
            lacc[i] += p.x + p.y + p.z + p.w;
            *(float4*)&P[4 * ty + i][4 * tx] = p;
        }
        __syncthreads();   // P ready

        // ---- O += P @ V ----
#pragma unroll 4
        for (int kk = 0; kk < TK; kk += 4) {
            float4 p0 = *(const float4*)&P[2 * pr][kk];
            float4 p1 = *(const float4*)&P[2 * pr + 1][kk];
            float4 v0 = *(const float4*)&V[kk + 0][pd];
            float4 v1 = *(const float4*)&V[kk + 1][pd];
            float4 v2 = *(const float4*)&V[kk + 2][pd];
            float4 v3 = *(const float4*)&V[kk + 3][pd];
            Oa0.x += p0.x * v0.x + p0.y * v1.x + p0.z * v2.x + p0.w * v3.x;
            Oa0.y += p0.x * v0.y + p0.y * v1.y + p0.z * v2.y + p0.w * v3.y;
            Oa0.z += p0.x * v0.z + p0.y * v1.z + p0.z * v2.z + p0.w * v3.z;
            Oa0.w += p0.x * v0.w + p0.y * v1.w + p0.z * v2.w + p0.w * v3.w;
            Oa1.x += p1.x * v0.x + p1.y * v1.x + p1.z * v2.x + p1.w * v3.x;
            Oa1.y += p1.x * v0.y + p1.y * v1.y + p1.z * v2.y + p1.w * v3.y;
            Oa1.z += p1.x * v0.z + p1.y * v1.z + p1.z * v2.z + p1.w * v3.z;
            Oa1.w += p1.x * v0.w + p1.y * v1.w + p1.z * v2.w + p1.w * v3.w;
        }
    }

    // ---- final: l reduce, normalize, write ----
#pragma unroll
    for (int i = 0; i < 4; ++i) lsum[4 * ty + i][tx] = lacc[i];
    __syncthreads();
    float l0 = 0.f, l1 = 0.f;
#pragma unroll
    for (int j = 0; j < 16; ++j) { l0 += lsum[2 * pr][j]; l1 += lsum[2 * pr + 1][j]; }
    float r0 = (l0 > 1e-30f) ? 1.0f / l0 : 0.0f;   // masked rows -> exact 0
    float r1 = (l1 > 1e-30f) ? 1.0f / l1 : 0.0f;
    float4 o0 = {Oa0.x * r0, Oa0.y * r0, Oa0.z * r0, Oa0.w * r0};
    float4 o1 = {Oa1.x * r1, Oa1.y * r1, Oa1.z * r1, Oa1.w * r1};
    *(float4*)(out + (size_t)(b * NB + q0 + 2 * pr) * DIMM + h * HD + pd) = o0;
    *(float4*)(out + (size_t)(b * NB + q0 + 2 * pr + 1) * DIMM + h * HD + pd) = o1;
}

// ---------------- launch ----------------
extern "C" void kernel_launch(void* const* d_in, const int* in_sizes, int n_in,
                              void* d_out, int out_size, void* d_ws, size_t ws_size,
                              hipStream_t stream) {
    const float* x       = (const float*)d_in[0];
    const int*   etypes  = (const int*)d_in[1];
    const void*  nmask   = d_in[2];
    const float* qkv_w   = (const float*)d_in[3];
    const float* qkv_b   = (const float*)d_in[4];
    const float* proj_w  = (const float*)d_in[5];
    const float* proj_b  = (const float*)d_in[6];
    const float* table   = (const float*)d_in[7];
    const float* ln1_g   = (const float*)d_in[8];
    const float* ln1_b   = (const float*)d_in[9];
    const float* ln2_g   = (const float*)d_in[10];
    const float* ln2_b   = (const float*)d_in[11];
    const float* ffn_w1  = (const float*)d_in[12];
    const float* ffn_b1  = (const float*)d_in[13];
    const float* ffn_w2  = (const float*)d_in[14];
    const float* ffn_b2  = (const float*)d_in[15];
    float* out = (float*)d_out;
    float* ws  = (float*)d_ws;

    float* h_ln   = ws;
    float* qkv    = ws + 1048576;
    float* attn_o = ws + 4194304;
    float* x1     = ws + 5242880;
    float* mid    = ws + 6291456;
    int*   flag   = (int*)(ws + 10485760);

    detect_mask_fmt<<<dim3(1), dim3(256), 0, stream>>>((const unsigned char*)nmask, flag);

    ln_kernel<<<dim3(ROWS), dim3(256), 0, stream>>>(x, ln1_g, ln1_b, h_ln);
    gemm_kernel<0><<<dim3(768/64, ROWS/64), dim3(256), 0, stream>>>(
        h_ln, qkv_w, qkv_b, qkv, ROWS, 768, 256, nullptr, nullptr, flag);
    attn_flash<<<dim3(NB/TQ, HEADS, BB), dim3(256), 0, stream>>>(
        qkv, etypes, table, nmask, flag, attn_o);
    gemm_kernel<1><<<dim3(256/64, ROWS/64), dim3(256), 0, stream>>>(
        attn_o, proj_w, proj_b, x1, ROWS, 256, 256, x, nmask, flag);
    ln_kernel<<<dim3(ROWS), dim3(256), 0, stream>>>(x1, ln2_g, ln2_b, h_ln);
    gemm_kernel<2><<<dim3(1024/64, ROWS/64), dim3(256), 0, stream>>>(
        h_ln, ffn_w1, ffn_b1, mid, ROWS, 1024, 256, nullptr, nullptr, flag);
    gemm_kernel<1><<<dim3(256/64, ROWS/64), dim3(256), 0, stream>>>(
        mid, ffn_w2, ffn_b2, out, ROWS, 256, 1024, x1, nmask, flag);
}

// Round 3
// 327.430 us; speedup vs baseline: 5.3955x; 1.4581x over previous
//
#include <hip/hip_runtime.h>
#include <math.h>

#define DIMM 256
#define HEADS 8
#define HD 32
#define NB 2048
#define BB 2
#define ROWS (BB*NB)   // 4096

typedef __attribute__((ext_vector_type(8))) short bf16x8;
typedef __attribute__((ext_vector_type(4))) float f32x4;

__device__ inline unsigned short f2bf(float f) {
    unsigned int u = __float_as_uint(f);
    u += 0x7FFFu + ((u >> 16) & 1u);           // RNE
    return (unsigned short)(u >> 16);
}

// ---------------- mask format handling ----------------
__global__ __launch_bounds__(256) void detect_mask_fmt(const unsigned char* __restrict__ nm,
                                                       int* __restrict__ flag) {
    __shared__ int red[256];
    int t = threadIdx.x;
    int cnt = 0;
    for (int i = t; i < 1024; i += 256) cnt += (nm[4*i + 1] != 0) ? 1 : 0;
    red[t] = cnt;
    __syncthreads();
    for (int s = 128; s > 0; s >>= 1) {
        if (t < s) red[t] += red[t + s];
        __syncthreads();
    }
    if (t == 0) *flag = (red[0] > 0) ? 1 : 0;   // 1 => bool8, 0 => int32
}

__device__ inline int get_mask(const void* nm, int fmt, int idx) {
    if (fmt) return ((const unsigned char*)nm)[idx] != 0;
    return ((const int*)nm)[idx] != 0;
}

// ---------------- LayerNorm ----------------
__global__ __launch_bounds__(256) void ln_kernel(const float* __restrict__ x,
                                                 const float* __restrict__ g,
                                                 const float* __restrict__ b,
                                                 float* __restrict__ out) {
    int row = blockIdx.x;
    int t = threadIdx.x;
    float v = x[(size_t)row * DIMM + t];
    float s = v, s2 = v * v;
#pragma unroll
    for (int off = 32; off >= 1; off >>= 1) {
        s  += __shfl_xor(s,  off, 64);
        s2 += __shfl_xor(s2, off, 64);
    }
    __shared__ float rs[8];
    int wave = t >> 6;
    if ((t & 63) == 0) { rs[wave * 2] = s; rs[wave * 2 + 1] = s2; }
    __syncthreads();
    float ts  = rs[0] + rs[2] + rs[4] + rs[6];
    float ts2 = rs[1] + rs[3] + rs[5] + rs[7];
    float mean = ts * (1.0f / DIMM);
    float var  = ts2 * (1.0f / DIMM) - mean * mean;
    float rstd = rsqrtf(var + 1e-5f);
    out[(size_t)row * DIMM + t] = (v - mean) * rstd * g[t] + b[t];
}

// ---------------- Tiled fp32 GEMM, fused epilogues ----------------
// EPI 1: (acc+bias)*mask[row] + resid ; EPI 2: gelu_exact(acc+bias)
template<int EPI>
__global__ __launch_bounds__(256) void gemm_kernel(
    const float* __restrict__ A, const float* __restrict__ Bw,
    const float* __restrict__ bias, float* __restrict__ C,
    int M, int Ncols, int K,
    const float* __restrict__ resid, const void* __restrict__ nmask,
    const int* __restrict__ fmt)
{
    __shared__ float As[16][68];
    __shared__ float Bs[16][64];
    int t  = threadIdx.x;
    int m0 = blockIdx.y * 64, n0 = blockIdx.x * 64;
    int ty = t >> 4, tx = t & 15;
    int ar = t >> 2, ac4 = t & 3;
    int br = t >> 4, bc4 = t & 15;
    float acc[4][4] = {};

    for (int k0 = 0; k0 < K; k0 += 16) {
        float4 a4 = *(const float4*)&A[(size_t)(m0 + ar) * K + k0 + ac4 * 4];
        As[ac4 * 4 + 0][ar] = a4.x;
        As[ac4 * 4 + 1][ar] = a4.y;
        As[ac4 * 4 + 2][ar] = a4.z;
        As[ac4 * 4 + 3][ar] = a4.w;
        float4 b4 = *(const float4*)&Bw[(size_t)(k0 + br) * Ncols + n0 + bc4 * 4];
        *(float4*)&Bs[br][bc4 * 4] = b4;
        __syncthreads();
#pragma unroll
        for (int kk = 0; kk < 16; ++kk) {
            float4 av = *(const float4*)&As[kk][ty * 4];
            float4 bv = *(const float4*)&Bs[kk][tx * 4];
            float a[4] = {av.x, av.y, av.z, av.w};
            float bb[4] = {bv.x, bv.y, bv.z, bv.w};
#pragma unroll
            for (int i = 0; i < 4; ++i)
#pragma unroll
                for (int j = 0; j < 4; ++j) acc[i][j] += a[i] * bb[j];
        }
        __syncthreads();
    }

    int fm = (EPI == 1) ? *fmt : 0;
#pragma unroll
    for (int i = 0; i < 4; ++i) {
        int row = m0 + ty * 4 + i;
        float mk = 1.0f;
        if (EPI == 1) mk = (float)get_mask(nmask, fm, row);
#pragma unroll
        for (int j = 0; j < 4; ++j) {
            int col = n0 + tx * 4 + j;
            float v = acc[i][j] + bias[col];
            if (EPI == 2) v = 0.5f * v * (1.0f + erff(v * 0.70710678118654752f));
            if (EPI == 1) v = v * mk + resid[(size_t)row * Ncols + col];
            C[(size_t)row * Ncols + col] = v;
        }
    }
}

// ---------------- qkv GEMM: fp32 compute, bf16 outputs ----------------
// cols 0..511  -> qkvh[row][512]  (q|k, bf16)
// cols 512..767-> vT[(b*8+h)*32+d][n]  (bf16, transposed for PV B-frags)
__global__ __launch_bounds__(256) void gemm_qkv(
    const float* __restrict__ A, const float* __restrict__ Bw,
    const float* __restrict__ bias,
    unsigned short* __restrict__ qkvh, unsigned short* __restrict__ vT)
{
    __shared__ float As[16][68];
    __shared__ float Bs[16][64];
    const int K = 256, Ncols = 768;
    int t  = threadIdx.x;
    int m0 = blockIdx.y * 64, n0 = blockIdx.x * 64;
    int ty = t >> 4, tx = t & 15;
    int ar = t >> 2, ac4 = t & 3;
    int br = t >> 4, bc4 = t & 15;
    float acc[4][4] = {};

    for (int k0 = 0; k0 < K; k0 += 16) {
        float4 a4 = *(const float4*)&A[(size_t)(m0 + ar) * K + k0 + ac4 * 4];
        As[ac4 * 4 + 0][ar] = a4.x;
        As[ac4 * 4 + 1][ar] = a4.y;
        As[ac4 * 4 + 2][ar] = a4.z;
        As[ac4 * 4 + 3][ar] = a4.w;
        float4 b4 = *(const float4*)&Bw[(size_t)(k0 + br) * Ncols + n0 + bc4 * 4];
        *(float4*)&Bs[br][bc4 * 4] = b4;
        __syncthreads();
#pragma unroll
        for (int kk = 0; kk < 16; ++kk) {
            float4 av = *(const float4*)&As[kk][ty * 4];
            float4 bv = *(const float4*)&Bs[kk][tx * 4];
            float a[4] = {av.x, av.y, av.z, av.w};
            float bb[4] = {bv.x, bv.y, bv.z, bv.w};
#pragma unroll
            for (int i = 0; i < 4; ++i)
#pragma unroll
                for (int j = 0; j < 4; ++j) acc[i][j] += a[i] * bb[j];
        }
        __syncthreads();
    }

    if (n0 < 512) {
#pragma unroll
        for (int i = 0; i < 4; ++i) {
            int row = m0 + ty * 4 + i;
            ushort4 u;
            u.x = f2bf(acc[i][0] + bias[n0 + tx * 4 + 0]);
            u.y = f2bf(acc[i][1] + bias[n0 + tx * 4 + 1]);
            u.z = f2bf(acc[i][2] + bias[n0 + tx * 4 + 2]);
            u.w = f2bf(acc[i][3] + bias[n0 + tx * 4 + 3]);
            *(ushort4*)&qkvh[(size_t)row * 512 + n0 + tx * 4] = u;
        }
    } else {
        int rowb = m0 + ty * 4;
        int bb_ = rowb >> 11, n = rowb & 2047;
#pragma unroll
        for (int j = 0; j < 4; ++j) {
            int col = n0 + tx * 4 + j - 512;
            int hh = col >> 5, d = col & 31;
            float bs = bias[n0 + tx * 4 + j];
            ushort4 u;
            u.x = f2bf(acc[0][j] + bs);
            u.y = f2bf(acc[1][j] + bs);
            u.z = f2bf(acc[2][j] + bs);
            u.w = f2bf(acc[3][j] + bs);
            *(ushort4*)&vT[(size_t)((bb_ * HEADS + hh) * 32 + d) * NB + n] = u;
        }
    }
}

// ---------------- MFMA attention: barrier-free per-wave flash ----------------
// Wave = 16 q-rows of (b,h). Frag layouts (gfx950 16x16x32, HW-verified):
//   A: [m=l&15][k=quad*8+j]  B: [k=quad*8+j][n=l&15]  C/D: [row=quad*4+reg][col=l&15]
__global__ __launch_bounds__(256) void attn_mfma(
    const unsigned short* __restrict__ qkvh,  // [4096][512] bf16: q|k
    const unsigned short* __restrict__ vT,    // [512][2048] bf16
    const int* __restrict__ etypes,
    const float* __restrict__ table,
    const void* __restrict__ nmask, const int* __restrict__ fmt,
    float* __restrict__ out)
{
    __shared__ float P[4][16][68];     // per-wave prob regions
    __shared__ float tab[72];
    __shared__ float maskadd[NB];      // 0 or -1e9 per key (this batch)

    int t = threadIdx.x;
    int w = t >> 6, l = t & 63;
    int l15 = l & 15, quad = l >> 4;
    int h = blockIdx.y, b = blockIdx.z;
    int q0 = blockIdx.x * 64 + w * 16;
    int fm = *fmt;

    if (t < 72) tab[t] = table[t];
    for (int i = t; i < NB; i += 256)
        maskadd[i] = get_mask(nmask, fm, b * NB + i) ? 0.0f : -1e9f;
    __syncthreads();

    const float scale = 0.17677669529663689f;   // 1/sqrt(32)

    // Q A-frag (persistent)
    bf16x8 aq = *(const bf16x8*)(qkvh + (size_t)(b * NB + q0 + l15) * 512 + h * 32 + quad * 8);

    const unsigned short* kp = qkvh + (size_t)(b * NB + l15) * 512 + 256 + h * 32 + quad * 8;
    const unsigned short* vp = vT + (size_t)((b * HEADS + h) * 32 + l15) * NB + quad * 8;
    const int* ep = etypes + (size_t)(b * NB + q0 + quad * 4) * NB + l15;

    float rowm[4];
#pragma unroll
    for (int r = 0; r < 4; ++r) rowm[r] = maskadd[q0 + quad * 4 + r];

    float lacc[4] = {0.f, 0.f, 0.f, 0.f};
    f32x4 O0 = {0.f, 0.f, 0.f, 0.f}, O1 = {0.f, 0.f, 0.f, 0.f};

    auto loadtile = [&](bf16x8 (&kf)[4], bf16x8 (&vf)[2][2], int (&ef)[4][4], int m0) {
#pragma unroll
        for (int ct = 0; ct < 4; ++ct)
            kf[ct] = *(const bf16x8*)(kp + (size_t)(m0 + ct * 16) * 512);
#pragma unroll
        for (int ks = 0; ks < 2; ++ks) {
            vf[ks][0] = *(const bf16x8*)(vp + m0 + ks * 32);
            vf[ks][1] = *(const bf16x8*)(vp + 16 * NB + m0 + ks * 32);
        }
#pragma unroll
        for (int r = 0; r < 4; ++r)
#pragma unroll
            for (int ct = 0; ct < 4; ++ct)
                ef[r][ct] = ep[(size_t)r * NB + m0 + ct * 16];
    };

    auto process = [&](const bf16x8 (&kf)[4], const bf16x8 (&vf)[2][2], const int (&ef)[4][4], int m0) {
        // QK^T + exp -> P  (per-wave region, no barriers)
#pragma unroll
        for (int ct = 0; ct < 4; ++ct) {
            f32x4 zero = {0.f, 0.f, 0.f, 0.f};
            f32x4 s = __builtin_amdgcn_mfma_f32_16x16x32_bf16(aq, kf[ct], zero, 0, 0, 0);
            int colg = m0 + ct * 16 + l15;
            float madd = maskadd[colg];
#pragma unroll
            for (int r = 0; r < 4; ++r) {
                int ee = ef[r][ct];
                float ad = ((ee != 0) || (colg == q0 + quad * 4 + r)) ? tab[ee * 8 + h] : -1e9f;
                float p = __expf(fmaf(s[r], scale, ad + madd + rowm[r]));
                lacc[r] += p;
                P[w][quad * 4 + r][ct * 16 + l15] = p;
            }
        }
        // PV: P A-frags from LDS (cvt to bf16), V B-frags from regs
#pragma unroll
        for (int ks = 0; ks < 2; ++ks) {
            float4 pa = *(const float4*)&P[w][l15][ks * 32 + quad * 8];
            float4 pb = *(const float4*)&P[w][l15][ks * 32 + quad * 8 + 4];
            union { bf16x8 v; unsigned short us[8]; } pu;
            pu.us[0] = f2bf(pa.x); pu.us[1] = f2bf(pa.y);
            pu.us[2] = f2bf(pa.z); pu.us[3] = f2bf(pa.w);
            pu.us[4] = f2bf(pb.x); pu.us[5] = f2bf(pb.y);
            pu.us[6] = f2bf(pb.z); pu.us[7] = f2bf(pb.w);
            O0 = __builtin_amdgcn_mfma_f32_16x16x32_bf16(pu.v, vf[ks][0], O0, 0, 0, 0);
            O1 = __builtin_amdgcn_mfma_f32_16x16x32_bf16(pu.v, vf[ks][1], O1, 0, 0, 0);
        }
    };

    bf16x8 kA[4], kB[4];
    bf16x8 vA[2][2], vB[2][2];
    int eA[4][4], eB[4][4];

    loadtile(kA, vA, eA, 0);
    for (int m0 = 0; m0 < NB; m0 += 128) {
        loadtile(kB, vB, eB, m0 + 64);
        process(kA, vA, eA, m0);
        if (m0 + 128 < NB) loadtile(kA, vA, eA, m0 + 128);
        process(kB, vB, eB, m0 + 64);
    }

    // normalize + write
#pragma unroll
    for (int r = 0; r < 4; ++r) {
        float s = lacc[r];
        s += __shfl_xor(s, 1); s += __shfl_xor(s, 2);
        s += __shfl_xor(s, 4); s += __shfl_xor(s, 8);
        float rinv = (s > 0.f) ? 1.0f / s : 0.0f;
        size_t row = (size_t)(b * NB + q0 + quad * 4 + r);
        out[row * DIMM + h * 32 + l15]      = O0[r] * rinv;
        out[row * DIMM + h * 32 + 16 + l15] = O1[r] * rinv;
    }
}

// ---------------- launch ----------------
extern "C" void kernel_launch(void* const* d_in, const int* in_sizes, int n_in,
                              void* d_out, int out_size, void* d_ws, size_t ws_size,
                              hipStream_t stream) {
    const float* x       = (const float*)d_in[0];
    const int*   etypes  = (const int*)d_in[1];
    const void*  nmask   = d_in[2];
    const float* qkv_w   = (const float*)d_in[3];
    const float* qkv_b   = (const float*)d_in[4];
    const float* proj_w  = (const float*)d_in[5];
    const float* proj_b  = (const float*)d_in[6];
    const float* table   = (const float*)d_in[7];
    const float* ln1_g   = (const float*)d_in[8];
    const float* ln1_b   = (const float*)d_in[9];
    const float* ln2_g   = (const float*)d_in[10];
    const float* ln2_b   = (const float*)d_in[11];
    const float* ffn_w1  = (const float*)d_in[12];
    const float* ffn_b1  = (const float*)d_in[13];
    const float* ffn_w2  = (const float*)d_in[14];
    const float* ffn_b2  = (const float*)d_in[15];
    float* out = (float*)d_out;
    float* ws  = (float*)d_ws;

    float* h_ln   = ws;                               // 1M floats
    float* attn_o = ws + 1048576;                     // 1M
    float* x1     = ws + 2097152;                     // 1M
    float* mid    = ws + 3145728;                     // 4M
    unsigned short* qkvh = (unsigned short*)(ws + 7340032);  // 2M ushorts
    unsigned short* vT   = (unsigned short*)(ws + 8388608);  // 1M ushorts
    int*   flag   = (int*)(ws + 9437184);

    detect_mask_fmt<<<dim3(1), dim3(256), 0, stream>>>((const unsigned char*)nmask, flag);

    ln_kernel<<<dim3(ROWS), dim3(256), 0, stream>>>(x, ln1_g, ln1_b, h_ln);
    gemm_qkv<<<dim3(768/64, ROWS/64), dim3(256), 0, stream>>>(h_ln, qkv_w, qkv_b, qkvh, vT);
    attn_mfma<<<dim3(NB/64, HEADS, BB), dim3(256), 0, stream>>>(
        qkvh, vT, etypes, table, nmask, flag, attn_o);
    gemm_kernel<1><<<dim3(256/64, ROWS/64), dim3(256), 0, stream>>>(
        attn_o, proj_w, proj_b, x1, ROWS, 256, 256, x, nmask, flag);
    ln_kernel<<<dim3(ROWS), dim3(256), 0, stream>>>(x1, ln2_g, ln2_b, h_ln);
    gemm_kernel<2><<<dim3(1024/64, ROWS/64), dim3(256), 0, stream>>>(
        h_ln, ffn_w1, ffn_b1, mid, ROWS, 1024, 256, nullptr, nullptr, flag);
    gemm_kernel<1><<<dim3(256/64, ROWS/64), dim3(256), 0, stream>>>(
        mid, ffn_w2, ffn_b2, out, ROWS, 256, 1024, x1, nmask, flag);
}

// Round 4
// 258.518 us; speedup vs baseline: 6.8337x; 1.2666x over previous
//
#include <hip/hip_runtime.h>
#include <math.h>

#define DIMM 256
#define HEADS 8
#define NB 2048
#define BB 2
#define ROWS (BB*NB)   // 4096

typedef __attribute__((ext_vector_type(8))) short bf16x8;
typedef __attribute__((ext_vector_type(4))) float f32x4;

__device__ inline unsigned short f2bf(float f) {
    unsigned int u = __float_as_uint(f);
    u += 0x7FFFu + ((u >> 16) & 1u);           // RNE
    return (unsigned short)(u >> 16);
}

// ---------------- mask format handling ----------------
__global__ __launch_bounds__(256) void detect_mask_fmt(const unsigned char* __restrict__ nm,
                                                       int* __restrict__ flag) {
    __shared__ int red[256];
    int t = threadIdx.x;
    int cnt = 0;
    for (int i = t; i < 1024; i += 256) cnt += (nm[4*i + 1] != 0) ? 1 : 0;
    red[t] = cnt;
    __syncthreads();
    for (int s = 128; s > 0; s >>= 1) {
        if (t < s) red[t] += red[t + s];
        __syncthreads();
    }
    if (t == 0) *flag = (red[0] > 0) ? 1 : 0;   // 1 => bool8, 0 => int32
}

__device__ inline int get_mask(const void* nm, int fmt, int idx) {
    if (fmt) return ((const unsigned char*)nm)[idx] != 0;
    return ((const int*)nm)[idx] != 0;
}

// ---------------- LayerNorm (bf16 out: feeds GEMM A-operands) ----------------
__global__ __launch_bounds__(256) void ln_kernel(const float* __restrict__ x,
                                                 const float* __restrict__ g,
                                                 const float* __restrict__ b,
                                                 unsigned short* __restrict__ out) {
    int row = blockIdx.x;
    int t = threadIdx.x;
    float v = x[(size_t)row * DIMM + t];
    float s = v, s2 = v * v;
#pragma unroll
    for (int off = 32; off >= 1; off >>= 1) {
        s  += __shfl_xor(s,  off, 64);
        s2 += __shfl_xor(s2, off, 64);
    }
    __shared__ float rs[8];
    int wave = t >> 6;
    if ((t & 63) == 0) { rs[wave * 2] = s; rs[wave * 2 + 1] = s2; }
    __syncthreads();
    float ts  = rs[0] + rs[2] + rs[4] + rs[6];
    float ts2 = rs[1] + rs[3] + rs[5] + rs[7];
    float mean = ts * (1.0f / DIMM);
    float var  = ts2 * (1.0f / DIMM) - mean * mean;
    float rstd = rsqrtf(var + 1e-5f);
    out[(size_t)row * DIMM + t] = f2bf((v - mean) * rstd * g[t] + b[t]);
}

// ---------------- weight fp32[K,N] -> bf16[N,K] transpose ----------------
__global__ __launch_bounds__(256) void w2bfT(
    const float* __restrict__ w0, const float* __restrict__ w1,
    const float* __restrict__ w2, const float* __restrict__ w3,
    unsigned short* __restrict__ o0, unsigned short* __restrict__ o1,
    unsigned short* __restrict__ o2, unsigned short* __restrict__ o3)
{
    __shared__ float tile[64][65];
    int bid = blockIdx.x;
    const float* src; unsigned short* dst; int K, N, idx;
    if (bid < 48)       { src = w0; dst = o0; K = 256;  N = 768;  idx = bid; }
    else if (bid < 64)  { src = w1; dst = o1; K = 256;  N = 256;  idx = bid - 48; }
    else if (bid < 128) { src = w2; dst = o2; K = 256;  N = 1024; idx = bid - 64; }
    else                { src = w3; dst = o3; K = 1024; N = 256;  idx = bid - 128; }
    int ntiles = N >> 6;
    int k0 = (idx / ntiles) * 64, n0 = (idx % ntiles) * 64;
    int t = threadIdx.x;
    int r = t >> 4, c4 = (t & 15) * 4;
#pragma unroll
    for (int i = 0; i < 4; ++i) {
        float4 v = *(const float4*)&src[(size_t)(k0 + r + i * 16) * N + n0 + c4];
        tile[r + i * 16][c4 + 0] = v.x;
        tile[r + i * 16][c4 + 1] = v.y;
        tile[r + i * 16][c4 + 2] = v.z;
        tile[r + i * 16][c4 + 3] = v.w;
    }
    __syncthreads();
#pragma unroll
    for (int i = 0; i < 4; ++i) {
        int n = n0 + r + i * 16;
        ushort4 u;
        u.x = f2bf(tile[c4 + 0][r + i * 16]);
        u.y = f2bf(tile[c4 + 1][r + i * 16]);
        u.z = f2bf(tile[c4 + 2][r + i * 16]);
        u.w = f2bf(tile[c4 + 3][r + i * 16]);
        *(ushort4*)&dst[(size_t)n * K + k0 + c4] = u;
    }
}

// ---------------- MFMA GEMM: C = A[M,K] @ Bt^T + bias, fused epilogues ----------------
// A bf16 row-major [M,K]; Bt bf16 [N,K] (weight pre-transposed).
// EPI 1: Cf = (acc+bias)*mask[row] + resid   (fp32 out)
// EPI 2: Ch = bf16(gelu_exact(acc+bias))
// MT = rows per block (64 or 128); 64 cols per block; 4 waves = 4 row-tiles of 16.
template<int EPI, int MT>
__global__ __launch_bounds__(256) void gemm_mfma(
    const unsigned short* __restrict__ A, const unsigned short* __restrict__ Bt,
    const float* __restrict__ bias, float* __restrict__ Cf,
    unsigned short* __restrict__ Ch, int Ncols, int K,
    const float* __restrict__ resid, const void* __restrict__ nmask,
    const int* __restrict__ fmt)
{
    constexpr int NH = MT / 64;
    int t = threadIdx.x, w = t >> 6, l = t & 63;
    int l15 = l & 15, quad = l >> 4;
    int n0 = blockIdx.x * 64;
    int m0 = blockIdx.y * MT;
    const unsigned short* ap = A + (size_t)(m0 + w * 16 + l15) * K + quad * 8;
    const unsigned short* bp = Bt + (size_t)(n0 + l15) * K + quad * 8;

    f32x4 acc[NH][4];
#pragma unroll
    for (int hh = 0; hh < NH; ++hh)
#pragma unroll
        for (int c = 0; c < 4; ++c) acc[hh][c] = (f32x4){0.f, 0.f, 0.f, 0.f};

    bf16x8 aA[NH], bA[4], aB[NH], bB[4];

    auto ld = [&](bf16x8 (&af)[NH], bf16x8 (&bf)[4], int k0) {
#pragma unroll
        for (int hh = 0; hh < NH; ++hh)
            af[hh] = *(const bf16x8*)(ap + (size_t)hh * 64 * K + k0);
#pragma unroll
        for (int c = 0; c < 4; ++c)
            bf[c] = *(const bf16x8*)(bp + (size_t)(c * 16) * K + k0);
    };
    auto pr = [&](const bf16x8 (&af)[NH], const bf16x8 (&bf)[4]) {
#pragma unroll
        for (int hh = 0; hh < NH; ++hh)
#pragma unroll
            for (int c = 0; c < 4; ++c)
                acc[hh][c] = __builtin_amdgcn_mfma_f32_16x16x32_bf16(af[hh], bf[c], acc[hh][c], 0, 0, 0);
    };

    ld(aA, bA, 0);
    for (int k0 = 0; k0 < K; k0 += 64) {
        ld(aB, bB, k0 + 32);
        pr(aA, bA);
        if (k0 + 64 < K) ld(aA, bA, k0 + 64);
        pr(aB, bB);
    }

    int fm = (EPI == 1) ? *fmt : 0;
#pragma unroll
    for (int hh = 0; hh < NH; ++hh)
#pragma unroll
        for (int r = 0; r < 4; ++r) {
            int row = m0 + hh * 64 + w * 16 + quad * 4 + r;
            float mk = (EPI == 1) ? (float)get_mask(nmask, fm, row) : 1.0f;
#pragma unroll
            for (int c = 0; c < 4; ++c) {
                int col = n0 + c * 16 + l15;
                float v = acc[hh][c][r] + bias[col];
                if (EPI == 2) {
                    v = 0.5f * v * (1.0f + erff(v * 0.70710678118654752f));
                    Ch[(size_t)row * Ncols + col] = f2bf(v);
                } else {
                    v = v * mk + resid[(size_t)row * Ncols + col];
                    Cf[(size_t)row * Ncols + col] = v;
                }
            }
        }
}

// ---------------- MFMA qkv GEMM: bf16 q|k rows + transposed bf16 V ----------------
__global__ __launch_bounds__(256) void gemm_qkv_mfma(
    const unsigned short* __restrict__ A, const unsigned short* __restrict__ Bt,
    const float* __restrict__ bias,
    unsigned short* __restrict__ qkvh, unsigned short* __restrict__ vT)
{
    const int K = 256;
    int t = threadIdx.x, w = t >> 6, l = t & 63;
    int l15 = l & 15, quad = l >> 4;
    int n0 = blockIdx.x * 64;
    int m0 = blockIdx.y * 128;
    const unsigned short* ap = A + (size_t)(m0 + w * 16 + l15) * K + quad * 8;
    const unsigned short* bp = Bt + (size_t)(n0 + l15) * K + quad * 8;

    f32x4 acc[2][4];
#pragma unroll
    for (int hh = 0; hh < 2; ++hh)
#pragma unroll
        for (int c = 0; c < 4; ++c) acc[hh][c] = (f32x4){0.f, 0.f, 0.f, 0.f};

    bf16x8 aA[2], bA[4], aB[2], bB[4];
    auto ld = [&](bf16x8 (&af)[2], bf16x8 (&bf)[4], int k0) {
#pragma unroll
        for (int hh = 0; hh < 2; ++hh)
            af[hh] = *(const bf16x8*)(ap + (size_t)hh * 64 * K + k0);
#pragma unroll
        for (int c = 0; c < 4; ++c)
            bf[c] = *(const bf16x8*)(bp + (size_t)(c * 16) * K + k0);
    };
    auto pr = [&](const bf16x8 (&af)[2], const bf16x8 (&bf)[4]) {
#pragma unroll
        for (int hh = 0; hh < 2; ++hh)
#pragma unroll
            for (int c = 0; c < 4; ++c)
                acc[hh][c] = __builtin_amdgcn_mfma_f32_16x16x32_bf16(af[hh], bf[c], acc[hh][c], 0, 0, 0);
    };
    ld(aA, bA, 0);
    for (int k0 = 0; k0 < K; k0 += 64) {
        ld(aB, bB, k0 + 32);
        pr(aA, bA);
        if (k0 + 64 < K) ld(aA, bA, k0 + 64);
        pr(aB, bB);
    }

    if (n0 < 512) {   // q|k region -> qkvh[row][512]
#pragma unroll
        for (int hh = 0; hh < 2; ++hh)
#pragma unroll
            for (int r = 0; r < 4; ++r) {
                int row = m0 + hh * 64 + w * 16 + quad * 4 + r;
#pragma unroll
                for (int c = 0; c < 4; ++c) {
                    int col = n0 + c * 16 + l15;
                    qkvh[(size_t)row * 512 + col] = f2bf(acc[hh][c][r] + bias[col]);
                }
            }
    } else {          // v region -> vT[(b*8+h)*32+d][n]
        int bb_ = m0 >> 11;
#pragma unroll
        for (int hh = 0; hh < 2; ++hh) {
            int n = (m0 + hh * 64 + w * 16 + quad * 4) & 2047;
#pragma unroll
            for (int c = 0; c < 4; ++c) {
                int col = n0 + c * 16 + l15 - 512;
                int hidx = col >> 5, d = col & 31;
                float bs = bias[n0 + c * 16 + l15];
                ushort4 u;
                u.x = f2bf(acc[hh][c][0] + bs);
                u.y = f2bf(acc[hh][c][1] + bs);
                u.z = f2bf(acc[hh][c][2] + bs);
                u.w = f2bf(acc[hh][c][3] + bs);
                *(ushort4*)&vT[(size_t)((bb_ * HEADS + hidx) * 32 + d) * NB + n] = u;
            }
        }
    }
}

// ---------------- MFMA attention, split-K=2, barrier-free per-wave flash ----------------
__global__ __launch_bounds__(256) void attn_mfma(
    const unsigned short* __restrict__ qkvh,  // [4096][512] bf16: q|k
    const unsigned short* __restrict__ vT,    // [512][2048] bf16
    const int* __restrict__ etypes,
    const float* __restrict__ table,
    const void* __restrict__ nmask, const int* __restrict__ fmt,
    float* __restrict__ Opart, float* __restrict__ lpart)
{
    __shared__ float P[4][16][68];
    __shared__ float tab[72];
    __shared__ float maskadd[NB];

    int t = threadIdx.x;
    int w = t >> 6, l = t & 63;
    int l15 = l & 15, quad = l >> 4;
    int h = blockIdx.y;
    int z = blockIdx.z, b = z >> 1, sp = z & 1;
    int q0 = blockIdx.x * 64 + w * 16;
    int kbase = sp * (NB / 2);
    int fm = *fmt;

    if (t < 72) tab[t] = table[t];
    for (int i = t; i < NB; i += 256)
        maskadd[i] = get_mask(nmask, fm, b * NB + i) ? 0.0f : -1e9f;
    __syncthreads();

    const float scale = 0.17677669529663689f;   // 1/sqrt(32)

    bf16x8 aq = *(const bf16x8*)(qkvh + (size_t)(b * NB + q0 + l15) * 512 + h * 32 + quad * 8);

    const unsigned short* kp = qkvh + (size_t)(b * NB + l15) * 512 + 256 + h * 32 + quad * 8;
    const unsigned short* vp = vT + (size_t)((b * HEADS + h) * 32 + l15) * NB + quad * 8;
    const int* ep = etypes + (size_t)(b * NB + q0 + quad * 4) * NB + l15;

    float rowm[4];
#pragma unroll
    for (int r = 0; r < 4; ++r) rowm[r] = maskadd[q0 + quad * 4 + r];

    float lacc[4] = {0.f, 0.f, 0.f, 0.f};
    f32x4 O0 = {0.f, 0.f, 0.f, 0.f}, O1 = {0.f, 0.f, 0.f, 0.f};

    auto loadtile = [&](bf16x8 (&kf)[4], bf16x8 (&vf)[2][2], int (&ef)[4][4], int m0) {
#pragma unroll
        for (int ct = 0; ct < 4; ++ct)
            kf[ct] = *(const bf16x8*)(kp + (size_t)(m0 + ct * 16) * 512);
#pragma unroll
        for (int ks = 0; ks < 2; ++ks) {
            vf[ks][0] = *(const bf16x8*)(vp + m0 + ks * 32);
            vf[ks][1] = *(const bf16x8*)(vp + 16 * NB + m0 + ks * 32);
        }
#pragma unroll
        for (int r = 0; r < 4; ++r)
#pragma unroll
            for (int ct = 0; ct < 4; ++ct)
                ef[r][ct] = ep[(size_t)r * NB + m0 + ct * 16];
    };

    auto process = [&](const bf16x8 (&kf)[4], const bf16x8 (&vf)[2][2], const int (&ef)[4][4], int m0) {
#pragma unroll
        for (int ct = 0; ct < 4; ++ct) {
            f32x4 zero = {0.f, 0.f, 0.f, 0.f};
            f32x4 s = __builtin_amdgcn_mfma_f32_16x16x32_bf16(aq, kf[ct], zero, 0, 0, 0);
            int colg = m0 + ct * 16 + l15;
            float madd = maskadd[colg];
#pragma unroll
            for (int r = 0; r < 4; ++r) {
                int ee = ef[r][ct];
                float ad = ((ee != 0) || (colg == q0 + quad * 4 + r)) ? tab[ee * 8 + h] : -1e9f;
                float p = __expf(fmaf(s[r], scale, ad + madd + rowm[r]));
                lacc[r] += p;
                P[w][quad * 4 + r][ct * 16 + l15] = p;
            }
        }
#pragma unroll
        for (int ks = 0; ks < 2; ++ks) {
            float4 pa = *(const float4*)&P[w][l15][ks * 32 + quad * 8];
            float4 pb = *(const float4*)&P[w][l15][ks * 32 + quad * 8 + 4];
            union { bf16x8 v; unsigned short us[8]; } pu;
            pu.us[0] = f2bf(pa.x); pu.us[1] = f2bf(pa.y);
            pu.us[2] = f2bf(pa.z); pu.us[3] = f2bf(pa.w);
            pu.us[4] = f2bf(pb.x); pu.us[5] = f2bf(pb.y);
            pu.us[6] = f2bf(pb.z); pu.us[7] = f2bf(pb.w);
            O0 = __builtin_amdgcn_mfma_f32_16x16x32_bf16(pu.v, vf[ks][0], O0, 0, 0, 0);
            O1 = __builtin_amdgcn_mfma_f32_16x16x32_bf16(pu.v, vf[ks][1], O1, 0, 0, 0);
        }
    };

    bf16x8 kA[4], kB[4];
    bf16x8 vA[2][2], vB[2][2];
    int eA[4][4], eB[4][4];

    loadtile(kA, vA, eA, kbase);
    for (int m0 = kbase; m0 < kbase + NB / 2; m0 += 128) {
        loadtile(kB, vB, eB, m0 + 64);
        process(kA, vA, eA, m0);
        if (m0 + 128 < kbase + NB / 2) loadtile(kA, vA, eA, m0 + 128);
        process(kB, vB, eB, m0 + 64);
    }

    float* Ob = Opart + (size_t)sp * ROWS * DIMM;
#pragma unroll
    for (int r = 0; r < 4; ++r) {
        float s = lacc[r];
        s += __shfl_xor(s, 1); s += __shfl_xor(s, 2);
        s += __shfl_xor(s, 4); s += __shfl_xor(s, 8);
        int row = b * NB + q0 + quad * 4 + r;
        Ob[(size_t)row * DIMM + h * 32 + l15]      = O0[r];
        Ob[(size_t)row * DIMM + h * 32 + 16 + l15] = O1[r];
        if (l15 == 0) lpart[(size_t)sp * ROWS * 8 + (size_t)row * 8 + h] = s;
    }
}

// ---------------- combine split-K partials, emit bf16 ----------------
__global__ __launch_bounds__(256) void attn_combine(
    const float* __restrict__ Op, const float* __restrict__ lp,
    unsigned short* __restrict__ attn_o)
{
    int row = blockIdx.x, t = threadIdx.x, h = t >> 5;
    float lsum = lp[(size_t)row * 8 + h] + lp[(size_t)(ROWS + row) * 8 + h];
    float o = Op[(size_t)row * DIMM + t] + Op[(size_t)ROWS * DIMM + (size_t)row * DIMM + t];
    float rinv = (lsum > 0.f) ? 1.0f / lsum : 0.0f;
    attn_o[(size_t)row * DIMM + t] = f2bf(o * rinv);
}

// ---------------- launch ----------------
extern "C" void kernel_launch(void* const* d_in, const int* in_sizes, int n_in,
                              void* d_out, int out_size, void* d_ws, size_t ws_size,
                              hipStream_t stream) {
    const float* x       = (const float*)d_in[0];
    const int*   etypes  = (const int*)d_in[1];
    const void*  nmask   = d_in[2];
    const float* qkv_w   = (const float*)d_in[3];
    const float* qkv_b   = (const float*)d_in[4];
    const float* proj_w  = (const float*)d_in[5];
    const float* proj_b  = (const float*)d_in[6];
    const float* table   = (const float*)d_in[7];
    const float* ln1_g   = (const float*)d_in[8];
    const float* ln1_b   = (const float*)d_in[9];
    const float* ln2_g   = (const float*)d_in[10];
    const float* ln2_b   = (const float*)d_in[11];
    const float* ffn_w1  = (const float*)d_in[12];
    const float* ffn_b1  = (const float*)d_in[13];
    const float* ffn_w2  = (const float*)d_in[14];
    const float* ffn_b2  = (const float*)d_in[15];
    float* out = (float*)d_out;
    float* ws  = (float*)d_ws;

    float* x1    = ws;                          // 1,048,576 f
    float* Opart = ws + 1048576;                // 2,097,152 f
    float* lpart = ws + 3145728;                // 65,536 f
    int*   flag  = (int*)(ws + 3211264);
    unsigned short* ub = (unsigned short*)(ws + 3211280);
    unsigned short* h_ln   = ub;                // 1,048,576 us
    unsigned short* qkvh   = ub + 1048576;      // 2,097,152
    unsigned short* vT     = ub + 3145728;      // 1,048,576
    unsigned short* attn_o = ub + 4194304;      // 1,048,576
    unsigned short* mid    = ub + 5242880;      // 4,194,304
    unsigned short* qkvT   = ub + 9437184;      // 196,608
    unsigned short* projT  = ub + 9633792;      // 65,536
    unsigned short* f1T    = ub + 9699328;      // 262,144
    unsigned short* f2T    = ub + 9961472;      // 262,144

    detect_mask_fmt<<<dim3(1), dim3(256), 0, stream>>>((const unsigned char*)nmask, flag);
    w2bfT<<<dim3(192), dim3(256), 0, stream>>>(qkv_w, proj_w, ffn_w1, ffn_w2,
                                               qkvT, projT, f1T, f2T);
    ln_kernel<<<dim3(ROWS), dim3(256), 0, stream>>>(x, ln1_g, ln1_b, h_ln);
    gemm_qkv_mfma<<<dim3(12, 32), dim3(256), 0, stream>>>(h_ln, qkvT, qkv_b, qkvh, vT);
    attn_mfma<<<dim3(NB/64, HEADS, BB*2), dim3(256), 0, stream>>>(
        qkvh, vT, etypes, table, nmask, flag, Opart, lpart);
    attn_combine<<<dim3(ROWS), dim3(256), 0, stream>>>(Opart, lpart, attn_o);
    gemm_mfma<1, 64><<<dim3(4, 64), dim3(256), 0, stream>>>(
        attn_o, projT, proj_b, x1, nullptr, 256, 256, x, nmask, flag);
    ln_kernel<<<dim3(ROWS), dim3(256), 0, stream>>>(x1, ln2_g, ln2_b, h_ln);
    gemm_mfma<2, 128><<<dim3(16, 32), dim3(256), 0, stream>>>(
        h_ln, f1T, ffn_b1, nullptr, mid, 1024, 256, nullptr, nullptr, flag);
    gemm_mfma<1, 64><<<dim3(4, 64), dim3(256), 0, stream>>>(
        mid, f2T, ffn_b2, out, nullptr, 256, 1024, x1, nmask, flag);
}